// Round 1
// baseline (2301.767 us; speedup 1.0000x reference)
//
#include <hip/hip_runtime.h>
#include <hip/hip_bf16.h>

// ---------------- problem constants ----------------
#define B_      512
#define KD_     256
#define VD_     512
#define M_      100000
#define CM_     64          // slots per chunk in main kernel
#define NCHUNK  1563        // ceil(100000/64)
#define CPR     (NCHUNK*8)  // candidates per row = 12504

// output element offsets (concatenated tuple, flat)
#define OUT_COMPOSED 0L
#define OUT_IDX      524288L
#define OUT_SIMV     528384L
#define OUT_GATT     532480L
#define OUT_SELIDX   864256L

// workspace float-element offsets
static constexpr long WS_FLAG = 0;
static constexpr long WS_QK   = 64;
static constexpr long WS_KPW  = WS_QK + 131072;     // kp_w natural [i][j]
static constexpr long WS_KPWT = WS_KPW + 65536;     // kp_w transposed [j][i]
static constexpr long WS_KPB  = WS_KPWT + 65536;
static constexpr long WS_OUT  = WS_KPB + 256;
static constexpr long WS_GATW = WS_OUT + 262144;
static constexpr long WS_GAS  = WS_GATW + 262144;
static constexpr long WS_GAD  = WS_GAS + 512;
static constexpr long WS_GAW  = WS_GAD + 512;
static constexpr long WS_GAB  = WS_GAW + 512;
static constexpr long WS_S1   = WS_GAB + 64;
static constexpr long WS_S2   = WS_S1 + 512;
static constexpr long WS_PKN  = WS_S2 + 512;        // pk normalized [512][256]
static constexpr long WS_SELI = WS_PKN + 131072;    // int[512*8] selected indices
static constexpr long WS_CANDV= WS_SELI + 4096;     // float[512*CPR]
static constexpr long WS_CANDI= WS_CANDV + (long)CPR*B_;  // int[512*CPR]

// ---------------- dual-dtype helpers ----------------
__device__ __forceinline__ float ldf(const void* p, long i, int isbf) {
  if (isbf) {
    unsigned short u = ((const unsigned short*)p)[i];
    return __uint_as_float(((unsigned)u) << 16);
  }
  return ((const float*)p)[i];
}
__device__ __forceinline__ void stf(void* p, long i, float v, int isbf) {
  if (isbf) ((__hip_bfloat16*)p)[i] = __float2bfloat16(v);
  else ((float*)p)[i] = v;
}

// ---------------- K0: detect input dtype ----------------
// s1 entries are exactly +-1.0.  f32: 0x3F800000/0xBF800000.
// bf16 pair packed in a dword: (0x3F80|0xBF80)(0x3F80|0xBF80).
__global__ void k_detect(const unsigned* s1, int* flag) {
  if (threadIdx.x == 0) {
    unsigned w = s1[0];
    *flag = ((w & 0x7FFF7FFFu) == 0x3F803F80u) ? 1 : 0;
  }
}

// ---------------- K1: stage constants as f32 in ws ----------------
__global__ void k_prep(const void* qk, const void* kpw, const void* kpb,
                       const void* outp, const void* gatw, const void* gas,
                       const void* gad, const void* gaw, const void* gab,
                       const void* s1, const void* s2, float* ws) {
  const int isbf = *(const int*)ws;
  long t = (long)blockIdx.x * blockDim.x + threadIdx.x;
  long stride = (long)gridDim.x * blockDim.x;
  for (long i = t; i < 131072; i += stride) ws[WS_QK + i]  = ldf(qk, i, isbf);
  for (long i = t; i < 65536;  i += stride) ws[WS_KPW + i] = ldf(kpw, i, isbf);
  for (long i = t; i < 65536;  i += stride) {
    long j = i >> 8, col = i & 255;                 // dst [j][col] = kp_w[col][j]
    ws[WS_KPWT + i] = ldf(kpw, col * 256 + j, isbf);
  }
  for (long i = t; i < 256;    i += stride) ws[WS_KPB + i] = ldf(kpb, i, isbf);
  for (long i = t; i < 262144; i += stride) ws[WS_OUT + i] = ldf(outp, i, isbf);
  for (long i = t; i < 262144; i += stride) ws[WS_GATW + i]= ldf(gatw, i, isbf);
  for (long i = t; i < 512;    i += stride) ws[WS_GAS + i] = ldf(gas, i, isbf);
  for (long i = t; i < 512;    i += stride) ws[WS_GAD + i] = ldf(gad, i, isbf);
  for (long i = t; i < 512;    i += stride) ws[WS_GAW + i] = ldf(gaw, i, isbf);
  for (long i = t; i < 1;      i += stride) ws[WS_GAB + i] = ldf(gab, i, isbf);
  for (long i = t; i < 512;    i += stride) ws[WS_S1 + i]  = ldf(s1, i, isbf);
  for (long i = t; i < 512;    i += stride) ws[WS_S2 + i]  = ldf(s2, i, isbf);
}

// ---------------- K2: pk_n = normalize(qk @ kp_w^T + b) ----------------
// 64 blocks x 256 threads; block handles 8 query rows.
__global__ void k_pk(float* ws) {
  __shared__ float qk_s[8][256];
  __shared__ float pk_s[8][260];
  __shared__ float kw_s[32][260];
  __shared__ float red[8][32];
  __shared__ float invs[8];
  const int t = threadIdx.x, blk = blockIdx.x;
  for (int n = 0; n < 2; ++n) {
    int e4 = t + 256 * n;              // 512 quads
    int r = e4 >> 6, j4 = e4 & 63;
    *(float4*)&qk_s[r][j4 * 4] =
      *(const float4*)&ws[WS_QK + (long)(blk * 8 + r) * 256 + j4 * 4];
  }
  const int il = t & 31, rg = t >> 5;
  for (int tile = 0; tile < 8; ++tile) {
    __syncthreads();
    for (int n = 0; n < 8; ++n) {
      int e4 = t + 256 * n;            // 2048 quads
      int ii = e4 >> 6, j4 = e4 & 63;
      *(float4*)&kw_s[ii][j4 * 4] =
        *(const float4*)&ws[WS_KPW + (long)(tile * 32 + ii) * 256 + j4 * 4];
    }
    __syncthreads();
    float acc = 0.f;
    for (int j = 0; j < 256; j += 4) {
      float4 a = *(const float4*)&qk_s[rg][j];
      float4 k4 = *(const float4*)&kw_s[il][j];
      acc += a.x * k4.x + a.y * k4.y + a.z * k4.z + a.w * k4.w;
    }
    pk_s[rg][tile * 32 + il] = acc + ws[WS_KPB + tile * 32 + il];
  }
  __syncthreads();
  {
    int r = t >> 5, c = t & 31;
    float s = 0.f;
    for (int q = 0; q < 8; ++q) { float v = pk_s[r][c + 32 * q]; s += v * v; }
    red[r][c] = s;
  }
  __syncthreads();
  if (t < 8) {
    float s = 0.f;
    for (int c = 0; c < 32; ++c) s += red[t][c];
    invs[t] = (float)(1.0 / fmax(sqrt((double)s), 1e-8));
  }
  __syncthreads();
  for (int n = 0; n < 8; ++n) {
    int e = t + 256 * n;               // 2048
    int r = e >> 8, i = e & 255;
    ws[WS_PKN + (long)(blk * 8 + r) * 256 + i] = pk_s[r][i] * invs[r];
  }
}

// ---------------- K3: fused project+normalize+sim+chunk-top8 ----------------
// grid = NCHUNK blocks of 512 threads, 1 block/CU (150KB LDS).
__global__ void __launch_bounds__(512) k_main(const void* key_store, float* ws) {
  extern __shared__ float sm[];
  float* psT   = sm;                       // [256][68]    (17408)
  float* reg2  = sm + 17408;               // union region (20544)
  float* key_lds = reg2;                   // ps phase: [64][256]
  float* kpw_t   = reg2 + 16384;           // ps phase: [16][260]
  float* pkT   = reg2;                     // sim phase: [64][132]
  float* simt  = reg2 + 8448;              // sim phase: [128][68]
  float* inv_s = sm + 17408 + 20544;       // [64]
  float* red_s = inv_s + 64;               // [512]

  const int isbf = *(const int*)ws;
  const int t = threadIdx.x;
  const int c = blockIdx.x;
  const long m_base = (long)c * CM_;

  // ---- stage key chunk [64][256] ----
  if (isbf) {
    const unsigned short* kp = (const unsigned short*)key_store;
    for (int n = 0; n < 8; ++n) {
      int e4 = t + 512 * n;
      int m = e4 >> 6, j4 = e4 & 63;
      float4 v;
      if (m_base + m < M_) {
        ushort4 u = *(const ushort4*)&kp[(m_base + m) * 256 + j4 * 4];
        v.x = __uint_as_float((unsigned)u.x << 16);
        v.y = __uint_as_float((unsigned)u.y << 16);
        v.z = __uint_as_float((unsigned)u.z << 16);
        v.w = __uint_as_float((unsigned)u.w << 16);
      } else v = make_float4(0.f, 0.f, 0.f, 0.f);
      *(float4*)&key_lds[m * 256 + j4 * 4] = v;
    }
  } else {
    const float* kp = (const float*)key_store;
    for (int n = 0; n < 8; ++n) {
      int e4 = t + 512 * n;
      int m = e4 >> 6, j4 = e4 & 63;
      float4 v = (m_base + m < M_)
        ? *(const float4*)&kp[(m_base + m) * 256 + j4 * 4]
        : make_float4(0.f, 0.f, 0.f, 0.f);
      *(float4*)&key_lds[m * 256 + j4 * 4] = v;
    }
  }

  // ---- ps GEMM: psT[i][m] = sum_j key[m][j]*kp_w[i][j] ----
  const int l = t & 63, g = t >> 6;        // g == wave id -> key reads are wave-broadcast
  const int i0 = l * 4;
  float acc[2][4][4] = {};
  for (int jt = 0; jt < 16; ++jt) {
    __syncthreads();
    for (int n = 0; n < 8; ++n) {
      int e = t + 512 * n;                 // 4096
      int jj = e >> 8, i = e & 255;
      kpw_t[jj * 260 + i] = ws[WS_KPWT + (long)(jt * 16 + jj) * 256 + i];
    }
    __syncthreads();
    #pragma unroll
    for (int jq = 0; jq < 4; ++jq) {
      float4 kw0 = *(const float4*)&kpw_t[(jq * 4 + 0) * 260 + i0];
      float4 kw1 = *(const float4*)&kpw_t[(jq * 4 + 1) * 260 + i0];
      float4 kw2 = *(const float4*)&kpw_t[(jq * 4 + 2) * 260 + i0];
      float4 kw3 = *(const float4*)&kpw_t[(jq * 4 + 3) * 260 + i0];
      float KW[4][4] = {{kw0.x, kw0.y, kw0.z, kw0.w},
                        {kw1.x, kw1.y, kw1.z, kw1.w},
                        {kw2.x, kw2.y, kw2.z, kw2.w},
                        {kw3.x, kw3.y, kw3.z, kw3.w}};
      #pragma unroll
      for (int pass = 0; pass < 2; ++pass) {
        int m0 = g * 8 + pass * 4;
        #pragma unroll
        for (int mm = 0; mm < 4; ++mm) {
          float4 av = *(const float4*)&key_lds[(m0 + mm) * 256 + jt * 16 + jq * 4];
          float A[4] = {av.x, av.y, av.z, av.w};
          #pragma unroll
          for (int q = 0; q < 4; ++q) {
            float s = acc[pass][q][mm];
            #pragma unroll
            for (int jj = 0; jj < 4; ++jj) s += KW[jj][q] * A[jj];
            acc[pass][q][mm] = s;
          }
        }
      }
    }
  }
  __syncthreads();
  #pragma unroll
  for (int pass = 0; pass < 2; ++pass)
    #pragma unroll
    for (int q = 0; q < 4; ++q) {
      float bias = ws[WS_KPB + i0 + q];
      #pragma unroll
      for (int mm = 0; mm < 4; ++mm) {
        int m = g * 8 + pass * 4 + mm;
        psT[(i0 + q) * 68 + m] = acc[pass][q][mm] + bias;
      }
    }
  __syncthreads();
  // ---- normalize ps columns ----
  {
    int m = t & 63, p = t >> 6;
    float s = 0.f;
    for (int q = 0; q < 32; ++q) { float v = psT[(p * 32 + q) * 68 + m]; s += v * v; }
    red_s[p * 64 + m] = s;
  }
  __syncthreads();
  if (t < 64) {
    float s = 0.f;
    for (int p = 0; p < 8; ++p) s += red_s[p * 64 + t];
    inv_s[t] = (float)(1.0 / fmax(sqrt((double)s), 1e-8));
  }
  __syncthreads();
  for (int n = 0; n < 32; ++n) {
    int e = t + 512 * n;                   // 16384
    int i = e >> 6, m = e & 63;
    psT[i * 68 + m] *= inv_s[m];
  }

  // ---- sim GEMM vs all 512 queries + chunk top-8 ----
  const int mo = t & 15, bo = t >> 4;
  const int m0 = mo * 4, b0 = bo * 4;
  float* cv = ws + WS_CANDV;
  int* ci = (int*)(ws + WS_CANDI);
  for (int bg = 0; bg < 4; ++bg) {
    float sa[4][4] = {};
    for (int ks = 0; ks < 4; ++ks) {
      __syncthreads();
      for (int n = 0; n < 4; ++n) {
        int e4 = t + 512 * n;              // 2048 quads
        int bb = e4 >> 4, k4 = e4 & 15;
        float4 v = *(const float4*)&ws[WS_PKN + (long)(bg * 128 + bb) * 256 + ks * 64 + k4 * 4];
        pkT[(k4 * 4 + 0) * 132 + bb] = v.x;
        pkT[(k4 * 4 + 1) * 132 + bb] = v.y;
        pkT[(k4 * 4 + 2) * 132 + bb] = v.z;
        pkT[(k4 * 4 + 3) * 132 + bb] = v.w;
      }
      __syncthreads();
      #pragma unroll 4
      for (int kq = 0; kq < 16; ++kq) {
        float4 p0 = *(const float4*)&psT[(ks * 64 + kq * 4 + 0) * 68 + m0];
        float4 p1 = *(const float4*)&psT[(ks * 64 + kq * 4 + 1) * 68 + m0];
        float4 p2 = *(const float4*)&psT[(ks * 64 + kq * 4 + 2) * 68 + m0];
        float4 p3 = *(const float4*)&psT[(ks * 64 + kq * 4 + 3) * 68 + m0];
        float4 q0 = *(const float4*)&pkT[(kq * 4 + 0) * 132 + b0];
        float4 q1 = *(const float4*)&pkT[(kq * 4 + 1) * 132 + b0];
        float4 q2 = *(const float4*)&pkT[(kq * 4 + 2) * 132 + b0];
        float4 q3 = *(const float4*)&pkT[(kq * 4 + 3) * 132 + b0];
        float P[4][4] = {{p0.x, p0.y, p0.z, p0.w}, {p1.x, p1.y, p1.z, p1.w},
                         {p2.x, p2.y, p2.z, p2.w}, {p3.x, p3.y, p3.z, p3.w}};
        float Q[4][4] = {{q0.x, q0.y, q0.z, q0.w}, {q1.x, q1.y, q1.z, q1.w},
                         {q2.x, q2.y, q2.z, q2.w}, {q3.x, q3.y, q3.z, q3.w}};
        #pragma unroll
        for (int kk = 0; kk < 4; ++kk)
          #pragma unroll
          for (int bb = 0; bb < 4; ++bb)
            #pragma unroll
            for (int mm = 0; mm < 4; ++mm)
              sa[bb][mm] += Q[kk][bb] * P[kk][mm];
      }
    }
    #pragma unroll
    for (int bb = 0; bb < 4; ++bb)
      #pragma unroll
      for (int mm = 0; mm < 4; ++mm)
        simt[(b0 + bb) * 68 + m0 + mm] = sa[bb][mm];
    __syncthreads();
    if (t < 128) {
      int row = t, b = bg * 128 + row;
      float tv[8]; int ti[8];
      #pragma unroll
      for (int q = 0; q < 8; ++q) { tv[q] = -3.0e38f; ti[q] = 0x7FFFFFFF; }
      int mmax = (int)(M_ - m_base); if (mmax > CM_) mmax = CM_;
      for (int m = 0; m < mmax; ++m) {
        float v = simt[row * 68 + m];
        if (v > tv[7]) {
          int s = (int)(m_base + m);
          bool placed = false;
          #pragma unroll
          for (int q = 7; q >= 1; --q) {
            if (!placed) {
              if (v > tv[q - 1]) { tv[q] = tv[q - 1]; ti[q] = ti[q - 1]; }
              else { tv[q] = v; ti[q] = s; placed = true; }
            }
          }
          if (!placed) { tv[0] = v; ti[0] = s; }
        }
      }
      long cb = (long)b * CPR + (long)c * 8;
      #pragma unroll
      for (int q = 0; q < 8; ++q) { cv[cb + q] = tv[q]; ci[cb + q] = ti[q]; }
    }
  }
}

// ---------------- K4: per-row merge -> top16 -> f64 rescore -> top8 ----------------
__global__ void k_topk(const void* key_store, const void* idx_store,
                       float* ws, void* dout) {
  __shared__ unsigned long long keys[256 * 16];
  __shared__ unsigned long long redk[256];
  __shared__ unsigned long long res[16];
  __shared__ int cidx[16];
  __shared__ double rv[16];
  const int isbf = *(const int*)ws;
  const int t = threadIdx.x, b = blockIdx.x;
  unsigned long long* ml = &keys[t * 16];
  #pragma unroll
  for (int q = 0; q < 16; ++q) ml[q] = 0ull;
  const float* cv = ws + WS_CANDV;
  const int* ci = (const int*)(ws + WS_CANDI);
  long base = (long)b * CPR;
  for (int cc = t; cc < CPR; cc += 256) {
    float v = cv[base + cc];
    unsigned id = (unsigned)ci[base + cc];
    unsigned bb = __float_as_uint(v);
    unsigned o = (bb & 0x80000000u) ? ~bb : (bb | 0x80000000u);
    unsigned long long key = ((unsigned long long)o << 32) |
                             (unsigned long long)(0xFFFFFFFFu - id);
    if (key > ml[15]) {
      int q = 15;
      while (q > 0 && key > ml[q - 1]) { ml[q] = ml[q - 1]; --q; }
      ml[q] = key;
    }
  }
  __syncthreads();
  int h = 0;
  for (int r = 0; r < 16; ++r) {
    redk[t] = (h < 16) ? ml[h] : 0ull;
    __syncthreads();
    for (int s = 128; s > 0; s >>= 1) {
      if (t < s) { if (redk[t + s] > redk[t]) redk[t] = redk[t + s]; }
      __syncthreads();
    }
    unsigned long long win = redk[0];
    if (h < 16 && ml[h] == win) ++h;
    if (t == 0) res[r] = win;
    __syncthreads();
  }
  if (t < 16) cidx[t] = (int)(0xFFFFFFFFu - (unsigned)(res[t] & 0xFFFFFFFFu));
  __syncthreads();
  // f64 rescore of 16 candidates (16 threads per candidate)
  {
    int cand = t >> 4, p = t & 15;
    long m = (long)cidx[cand];
    double dp = 0.0, nr = 0.0;
    for (int ii = 0; ii < 16; ++ii) {
      int i = p * 16 + ii;
      double s = (double)ws[WS_KPB + i];
      const float* wrow = ws + WS_KPW + (long)i * 256;
      if (isbf) {
        const unsigned short* kr = (const unsigned short*)key_store + m * 256;
        for (int j = 0; j < 256; ++j)
          s += (double)__uint_as_float((unsigned)kr[j] << 16) * (double)wrow[j];
      } else {
        const float* kr = (const float*)key_store + m * 256;
        for (int j = 0; j < 256; ++j)
          s += (double)kr[j] * (double)wrow[j];
      }
      dp += s * (double)ws[WS_PKN + (long)b * 256 + i];
      nr += s * s;
    }
    dp += __shfl_xor(dp, 1); nr += __shfl_xor(nr, 1);
    dp += __shfl_xor(dp, 2); nr += __shfl_xor(nr, 2);
    dp += __shfl_xor(dp, 4); nr += __shfl_xor(nr, 4);
    dp += __shfl_xor(dp, 8); nr += __shfl_xor(nr, 8);
    if (p == 0) rv[cand] = dp / fmax(sqrt(nr), 1e-8);
  }
  __syncthreads();
  if (t == 0) {
    int ordr[16];
    for (int q = 0; q < 16; ++q) ordr[q] = q;
    for (int a = 0; a < 8; ++a) {
      int best = a;
      for (int x = a + 1; x < 16; ++x) {
        int xi = ordr[x], bi = ordr[best];
        if (rv[xi] > rv[bi] || (rv[xi] == rv[bi] && cidx[xi] < cidx[bi])) best = x;
      }
      int tmp = ordr[a]; ordr[a] = ordr[best]; ordr[best] = tmp;
    }
    int* seli = (int*)(ws + WS_SELI);
    for (int r = 0; r < 8; ++r) {
      int m = cidx[ordr[r]];
      stf(dout, OUT_IDX + b * 8 + r, (float)m, isbf);
      stf(dout, OUT_SIMV + b * 8 + r, (float)rv[ordr[r]], isbf);
      stf(dout, OUT_SELIDX + b * 8 + r, ldf(idx_store, m, isbf), isbf);
      seli[b * 8 + r] = m;
    }
  }
}

// ---------------- K5: GAT compose + count-sketch + circular conv ----------------
__global__ void k_compose(const void* value_store, const int* h1, const int* h2,
                          float* ws, void* dout) {
  __shared__ float feats[9][512];          // later reused as gat_out
  __shared__ float Wh[9][512];
  __shared__ float g0[9][8];
  __shared__ float sd_[2][9][8];
  __shared__ float psi1[512], psi2[512], pooled[512];
  __shared__ float wk[9];
  __shared__ float redz[40];
  __shared__ int sel[8];
  const int isbf = *(const int*)ws;
  const int t = threadIdx.x, b = blockIdx.x;
  if (t < 8) sel[t] = ((const int*)(ws + WS_SELI))[b * 8 + t];
  feats[0][t]       = ws[WS_OUT + (long)b * 512 + t];
  feats[0][t + 256] = ws[WS_OUT + (long)b * 512 + t + 256];
  __syncthreads();
  for (int n = 0; n < 16; ++n) {
    int e = t + 256 * n;                   // 4096
    int r = e >> 9, d = e & 511;
    feats[1 + r][d] = ldf(value_store, (long)sel[r] * 512 + d, isbf);
  }
  __syncthreads();
  // Wh[k][he] = sum_d feats[k][d] * gat_w[d][he]
  {
    const int he0 = t, he1 = t + 256;
    float a0[9] = {}, a1[9] = {};
    const float* gw = ws + WS_GATW;
    for (int d = 0; d < 512; ++d) {
      float w0 = gw[(long)d * 512 + he0];
      float w1 = gw[(long)d * 512 + he1];
      #pragma unroll
      for (int k = 0; k < 9; ++k) {
        float a = feats[k][d];
        a0[k] += a * w0;
        a1[k] += a * w1;
      }
    }
    #pragma unroll
    for (int k = 0; k < 9; ++k) { Wh[k][he0] = a0[k]; Wh[k][he1] = a1[k]; }
  }
  __syncthreads();
  if (t < 144) {
    int k = t >> 4, rem = t & 15, hh = rem >> 1, sdx = rem & 1;
    const float* av = ws + (sdx ? WS_GAD : WS_GAS) + hh * 64;
    float s = 0.f;
    for (int e = 0; e < 64; ++e) s += Wh[k][hh * 64 + e] * av[e];
    sd_[sdx][k][hh] = s;
  }
  __syncthreads();
  if (t < 8) {   // row-0 softmax over all 9 neighbors
    float L[9], mx = -3e38f;
    for (int j = 0; j < 9; ++j) {
      float x = sd_[0][0][t] + sd_[1][j][t];
      L[j] = x > 0.f ? x : 0.2f * x;
      mx = fmaxf(mx, L[j]);
    }
    float ssum = 0.f;
    for (int j = 0; j < 9; ++j) { L[j] = expf(L[j] - mx); ssum += L[j]; }
    for (int j = 0; j < 9; ++j) g0[j][t] = L[j] / ssum;
  }
  __syncthreads();
  for (int n = 0; n < 3; ++n) {            // g_att output [9][9][8]
    int e = t + 256 * n;
    if (e < 648) {
      int i = e / 72, rem = e % 72, j = rem >> 3, hh = rem & 7;
      float v = (i == 0) ? g0[j][hh] : ((i == j) ? 1.0f : 0.0f);
      stf(dout, OUT_GATT + (long)b * 648 + e, v, isbf);
    }
  }
  __syncthreads();
  // gat_out (elu) into feats
  #pragma unroll
  for (int i = 0; i < 9; ++i) {
    for (int half = 0; half < 2; ++half) {
      int d = t + half * 256;
      float x;
      if (i == 0) {
        int hh = d >> 6;
        x = 0.f;
        #pragma unroll
        for (int j = 0; j < 9; ++j) x += g0[j][hh] * Wh[j][d];
      } else x = Wh[i][d];
      feats[i][d] = x > 0.f ? x : expm1f(x);
    }
  }
  __syncthreads();
  // node-pool weights
  {
    float part[9];
    const float* aw = ws + WS_GAW;
    #pragma unroll
    for (int k = 0; k < 9; ++k)
      part[k] = feats[k][t] * aw[t] + feats[k][t + 256] * aw[t + 256];
    #pragma unroll
    for (int k = 0; k < 9; ++k) {
      float s = part[k];
      s += __shfl_xor(s, 1);  s += __shfl_xor(s, 2);  s += __shfl_xor(s, 4);
      s += __shfl_xor(s, 8);  s += __shfl_xor(s, 16); s += __shfl_xor(s, 32);
      if ((t & 63) == 0) redz[(t >> 6) * 9 + k] = s;
    }
  }
  __syncthreads();
  if (t == 0) {
    float l[9], mx = -3e38f;
    for (int k = 0; k < 9; ++k) {
      l[k] = redz[k] + redz[9 + k] + redz[18 + k] + redz[27 + k] + ws[WS_GAB];
      mx = fmaxf(mx, l[k]);
    }
    float ssum = 0.f;
    for (int k = 0; k < 9; ++k) { l[k] = expf(l[k] - mx); ssum += l[k]; }
    for (int k = 0; k < 9; ++k) wk[k] = l[k] / ssum;
  }
  __syncthreads();
  for (int half = 0; half < 2; ++half) {
    int d = t + half * 256;
    float s = 0.f;
    #pragma unroll
    for (int k = 0; k < 9; ++k) s += wk[k] * feats[k][d];
    pooled[d] = s;
    psi1[d] = 0.f; psi2[d] = 0.f;
  }
  __syncthreads();
  for (int half = 0; half < 2; ++half) {
    int j = t + half * 256;
    atomicAdd(&psi1[h1[j]], ws[WS_OUT + (long)b * 512 + j] * ws[WS_S1 + j]);
    atomicAdd(&psi2[h2[j]], pooled[j] * ws[WS_S2 + j]);
  }
  __syncthreads();
  for (int half = 0; half < 2; ++half) {
    int tt = t + half * 256;
    float s = 0.f;
    for (int j = 0; j < 512; ++j) s += psi1[j] * psi2[(tt - j) & 511];
    stf(dout, OUT_COMPOSED + (long)b * 1024 + tt, s, isbf);
    stf(dout, OUT_COMPOSED + (long)b * 1024 + 512 + tt,
        ws[WS_OUT + (long)b * 512 + tt], isbf);
  }
}

// ---------------- launch ----------------
extern "C" void kernel_launch(void* const* d_in, const int* in_sizes, int n_in,
                              void* d_out, int out_size, void* d_ws, size_t ws_size,
                              hipStream_t stream) {
  float* ws = (float*)d_ws;
  // input order: 0 out, 1 query_key, 2 idx, 3 key_store, 4 value_store,
  // 5 idx_store, 6 kp_w, 7 kp_b, 8 gat_w, 9 gat_a_src, 10 gat_a_dst,
  // 11 gat_att_w, 12 gat_att_b, 13 h1, 14 h2, 15 s1, 16 s2
  k_detect<<<1, 64, 0, stream>>>((const unsigned*)d_in[15], (int*)d_ws);
  k_prep<<<512, 256, 0, stream>>>(d_in[1], d_in[6], d_in[7], d_in[0], d_in[8],
                                  d_in[9], d_in[10], d_in[11], d_in[12],
                                  d_in[15], d_in[16], ws);
  k_pk<<<64, 256, 0, stream>>>(ws);
  size_t smem = 38528 * sizeof(float);     // 154112 B dynamic LDS
  hipFuncSetAttribute((const void*)k_main,
                      hipFuncAttributeMaxDynamicSharedMemorySize, (int)smem);
  k_main<<<NCHUNK, 512, smem, stream>>>(d_in[3], ws);
  k_topk<<<512, 256, 0, stream>>>(d_in[3], d_in[5], ws, d_out);
  k_compose<<<512, 256, 0, stream>>>(d_in[4], (const int*)d_in[13],
                                     (const int*)d_in[14], ws, d_out);
}

// Round 2
// 1600.962 us; speedup vs baseline: 1.4377x; 1.4377x over previous
//
#include <hip/hip_runtime.h>
#include <hip/hip_bf16.h>

// ---------------- problem constants ----------------
#define B_      512
#define KD_     256
#define VD_     512
#define M_      100000
#define NPS     1563        // ceil(100000/64) blocks for k_ps
#define NST     391         // ceil(100000/256) slot tiles for k_sim
#define CPR2    (NST*8)     // candidates per row = 3128

// output element offsets (concatenated tuple, flat)
#define OUT_COMPOSED 0L
#define OUT_IDX      524288L
#define OUT_SIMV     528384L
#define OUT_GATT     532480L
#define OUT_SELIDX   864256L

typedef __attribute__((ext_vector_type(8))) short bf16x8;
typedef __attribute__((ext_vector_type(4))) float f32x4;

// workspace float-element offsets (keep 16-float alignment for bf16 regions)
static constexpr long WS_FLAG = 0;
static constexpr long WS_QK   = 64;                  // 131072
static constexpr long WS_KPW  = WS_QK + 131072;      // 65536 (kp_w natural [i][j], f32)
static constexpr long WS_KPB  = WS_KPW + 65536;      // 256
static constexpr long WS_OUT  = WS_KPB + 256;        // 262144
static constexpr long WS_GATW = WS_OUT + 262144;     // 262144
static constexpr long WS_GAS  = WS_GATW + 262144;    // 512
static constexpr long WS_GAD  = WS_GAS + 512;        // 512
static constexpr long WS_GAW  = WS_GAD + 512;        // 512
static constexpr long WS_GAB  = WS_GAW + 512;        // 64
static constexpr long WS_S1   = WS_GAB + 64;         // 512
static constexpr long WS_S2   = WS_S1 + 512;         // 512
static constexpr long WS_PKN  = WS_S2 + 512;         // 131072 (pk normalized f32)
static constexpr long WS_SELI = WS_PKN + 131072;     // int[512*8]
static constexpr long WS_PKBF = WS_SELI + 4096;      // bf16[512*256]  = 65536 floats
static constexpr long WS_KPWB = WS_PKBF + 65536;     // bf16[256*256]  = 32768 floats
static constexpr long WS_PSBF = WS_KPWB + 32768;     // bf16[100000*256] = 12800000 floats
static constexpr long WS_CANDV= WS_PSBF + 12800000;  // float[512*CPR2]
static constexpr long WS_CANDI= WS_CANDV + (long)CPR2 * B_; // int[512*CPR2]

// ---------------- helpers ----------------
__device__ __forceinline__ float ldf(const void* p, long i, int isbf) {
  if (isbf) {
    unsigned short u = ((const unsigned short*)p)[i];
    return __uint_as_float(((unsigned)u) << 16);
  }
  return ((const float*)p)[i];
}
__device__ __forceinline__ void stf(void* p, long i, float v, int isbf) {
  if (isbf) ((__hip_bfloat16*)p)[i] = __float2bfloat16(v);
  else ((float*)p)[i] = v;
}
__device__ __forceinline__ unsigned short f2bf(float f) {
  union { float f; unsigned u; } x; x.f = f;
  unsigned r = x.u + 0x7FFFu + ((x.u >> 16) & 1u);   // RNE
  return (unsigned short)(r >> 16);
}

// ---------------- K0: detect input dtype ----------------
__global__ void k_detect(const unsigned* s1, int* flag) {
  if (threadIdx.x == 0) {
    unsigned w = s1[0];
    *flag = ((w & 0x7FFF7FFFu) == 0x3F803F80u) ? 1 : 0;
  }
}

// ---------------- K1: stage constants as f32 (+bf16 kp_w) in ws ----------------
__global__ void k_prep(const void* qk, const void* kpw, const void* kpb,
                       const void* outp, const void* gatw, const void* gas,
                       const void* gad, const void* gaw, const void* gab,
                       const void* s1, const void* s2, float* ws) {
  const int isbf = *(const int*)ws;
  long t = (long)blockIdx.x * blockDim.x + threadIdx.x;
  long stride = (long)gridDim.x * blockDim.x;
  unsigned short* kpwb = (unsigned short*)(ws + WS_KPWB);
  for (long i = t; i < 131072; i += stride) ws[WS_QK + i]  = ldf(qk, i, isbf);
  for (long i = t; i < 65536;  i += stride) {
    float v = ldf(kpw, i, isbf);
    ws[WS_KPW + i] = v;
    kpwb[i] = f2bf(v);
  }
  for (long i = t; i < 256;    i += stride) ws[WS_KPB + i] = ldf(kpb, i, isbf);
  for (long i = t; i < 262144; i += stride) ws[WS_OUT + i] = ldf(outp, i, isbf);
  for (long i = t; i < 262144; i += stride) ws[WS_GATW + i]= ldf(gatw, i, isbf);
  for (long i = t; i < 512;    i += stride) ws[WS_GAS + i] = ldf(gas, i, isbf);
  for (long i = t; i < 512;    i += stride) ws[WS_GAD + i] = ldf(gad, i, isbf);
  for (long i = t; i < 512;    i += stride) ws[WS_GAW + i] = ldf(gaw, i, isbf);
  for (long i = t; i < 1;      i += stride) ws[WS_GAB + i] = ldf(gab, i, isbf);
  for (long i = t; i < 512;    i += stride) ws[WS_S1 + i]  = ldf(s1, i, isbf);
  for (long i = t; i < 512;    i += stride) ws[WS_S2 + i]  = ldf(s2, i, isbf);
}

// ---------------- K2: pk_n = normalize(qk @ kp_w^T + b), f32 + bf16 copies ----------------
__global__ void k_pk(float* ws) {
  __shared__ float qk_s[8][256];
  __shared__ float pk_s[8][260];
  __shared__ float kw_s[32][260];
  __shared__ float red[8][32];
  __shared__ float invs[8];
  const int t = threadIdx.x, blk = blockIdx.x;
  for (int n = 0; n < 2; ++n) {
    int e4 = t + 256 * n;
    int r = e4 >> 6, j4 = e4 & 63;
    *(float4*)&qk_s[r][j4 * 4] =
      *(const float4*)&ws[WS_QK + (long)(blk * 8 + r) * 256 + j4 * 4];
  }
  const int il = t & 31, rg = t >> 5;
  for (int tile = 0; tile < 8; ++tile) {
    __syncthreads();
    for (int n = 0; n < 8; ++n) {
      int e4 = t + 256 * n;
      int ii = e4 >> 6, j4 = e4 & 63;
      *(float4*)&kw_s[ii][j4 * 4] =
        *(const float4*)&ws[WS_KPW + (long)(tile * 32 + ii) * 256 + j4 * 4];
    }
    __syncthreads();
    float acc = 0.f;
    for (int j = 0; j < 256; j += 4) {
      float4 a = *(const float4*)&qk_s[rg][j];
      float4 k4 = *(const float4*)&kw_s[il][j];
      acc += a.x * k4.x + a.y * k4.y + a.z * k4.z + a.w * k4.w;
    }
    pk_s[rg][tile * 32 + il] = acc + ws[WS_KPB + tile * 32 + il];
  }
  __syncthreads();
  {
    int r = t >> 5, c = t & 31;
    float s = 0.f;
    for (int q = 0; q < 8; ++q) { float v = pk_s[r][c + 32 * q]; s += v * v; }
    red[r][c] = s;
  }
  __syncthreads();
  if (t < 8) {
    float s = 0.f;
    for (int c = 0; c < 32; ++c) s += red[t][c];
    invs[t] = (float)(1.0 / fmax(sqrt((double)s), 1e-8));
  }
  __syncthreads();
  unsigned short* pkbf = (unsigned short*)(ws + WS_PKBF);
  for (int n = 0; n < 8; ++n) {
    int e = t + 256 * n;
    int r = e >> 8, i = e & 255;
    float pv = pk_s[r][i] * invs[r];
    long gi = (long)(blk * 8 + r) * 256 + i;
    ws[WS_PKN + gi] = pv;
    pkbf[gi] = f2bf(pv);
  }
}

// ---------------- K3a: ps projection via MFMA -> normalized bf16 ps rows ----------------
// 1563 blocks x 256 threads (4 waves), each block = 64 slots.
__global__ void __launch_bounds__(256) k_ps(const void* key_store, float* ws) {
  __shared__ unsigned short key_s[64 * 264];     // 33792 B (pad 8 bf16/row)
  const int isbf = *(const int*)ws;
  const int t = threadIdx.x;
  const long m_base = (long)blockIdx.x * 64;
  const unsigned short* kpwb = (const unsigned short*)(ws + WS_KPWB);
  unsigned short* psbf = (unsigned short*)(ws + WS_PSBF);

  if (isbf) {
    const unsigned short* kp = (const unsigned short*)key_store;
    for (int n = 0; n < 16; ++n) {
      int idx = t + 256 * n;                     // 4096 4-elem chunks
      int m = idx >> 6, j4 = idx & 63;
      uint2 u = make_uint2(0u, 0u);
      if (m_base + m < M_) u = *(const uint2*)&kp[(m_base + m) * 256 + j4 * 4];
      *(uint2*)&key_s[m * 264 + j4 * 4] = u;
    }
  } else {
    const float* kp = (const float*)key_store;
    for (int n = 0; n < 16; ++n) {
      int idx = t + 256 * n;
      int m = idx >> 6, j4 = idx & 63;
      uint2 u = make_uint2(0u, 0u);
      if (m_base + m < M_) {
        float4 v = *(const float4*)&kp[(m_base + m) * 256 + j4 * 4];
        u.x = (unsigned)f2bf(v.x) | ((unsigned)f2bf(v.y) << 16);
        u.y = (unsigned)f2bf(v.z) | ((unsigned)f2bf(v.w) << 16);
      }
      *(uint2*)&key_s[m * 264 + j4 * 4] = u;
    }
  }
  __syncthreads();

  const int lane = t & 63, wv = t >> 6;
  const int n16 = lane & 15, quad = lane >> 4;
  f32x4 acc[16] = {};
  const unsigned short* arow = &key_s[(wv * 16 + n16) * 264];
  for (int ks = 0; ks < 8; ++ks) {
    bf16x8 a = *(const bf16x8*)&arow[ks * 32 + quad * 8];
    const unsigned short* bp = kpwb + n16 * 256 + ks * 32 + quad * 8;
    #pragma unroll
    for (int it = 0; it < 16; ++it) {
      bf16x8 b = *(const bf16x8*)&bp[it * 4096];
      acc[it] = __builtin_amdgcn_mfma_f32_16x16x32_bf16(a, b, acc[it], 0, 0, 0);
    }
  }
  // bias + row norms (rows m = wv*16 + quad*4 + r; cols i = it*16 + n16)
  float ss[4] = {0.f, 0.f, 0.f, 0.f};
  #pragma unroll
  for (int it = 0; it < 16; ++it) {
    float bias = ws[WS_KPB + it * 16 + n16];
    acc[it][0] += bias; acc[it][1] += bias; acc[it][2] += bias; acc[it][3] += bias;
    #pragma unroll
    for (int r = 0; r < 4; ++r) ss[r] += acc[it][r] * acc[it][r];
  }
  #pragma unroll
  for (int r = 0; r < 4; ++r) {
    ss[r] += __shfl_xor(ss[r], 1); ss[r] += __shfl_xor(ss[r], 2);
    ss[r] += __shfl_xor(ss[r], 4); ss[r] += __shfl_xor(ss[r], 8);
    ss[r] = 1.0f / fmaxf(sqrtf(ss[r]), 1e-8f);
  }
  // normalized bf16 back into LDS (per-wave-disjoint rows; no barrier needed)
  #pragma unroll
  for (int it = 0; it < 16; ++it) {
    int col = it * 16 + n16;
    #pragma unroll
    for (int r = 0; r < 4; ++r)
      key_s[(wv * 16 + quad * 4 + r) * 264 + col] = f2bf(acc[it][r] * ss[r]);
  }
  __syncthreads();
  // coalesced store to ws psbf [m][256] bf16
  for (int n = 0; n < 8; ++n) {
    int idx = t + 256 * n;                       // 2048 8-elem chunks
    int m = idx >> 5, c8 = idx & 31;
    if (m_base + m < M_)
      *(uint4*)&psbf[(m_base + m) * 256 + c8 * 8] =
        *(const uint4*)&key_s[m * 264 + c8 * 8];
  }
}

// ---------------- K3b: sim via MFMA + per-256-slot-chunk exact top-8 ----------------
// grid = 8 qtiles x 391 stiles (qtile fast for L3 reuse), 512 threads (8 waves).
#define SIMW 261
__global__ void __launch_bounds__(512) k_sim(float* ws) {
  extern __shared__ char smem8[];
  unsigned short* pk_s = (unsigned short*)smem8;            // 64 x 264 bf16 = 33792 B
  unsigned short* ps_s = (unsigned short*)(smem8 + 33792);  // 256 x 136 bf16 = 69632 B
  float* simt  = (float*)smem8;                             // 64 x 261 f32 = 66816 B
  float* candv = (float*)(smem8 + 66816);                   // 128 x 8
  int*   candi = (int*)(smem8 + 66816 + 4096);              // 128 x 8

  const int t = threadIdx.x;
  const int qtile = blockIdx.x & 7, stile = blockIdx.x >> 3;
  const int qbase = qtile * 64;
  const long sbase = (long)stile * 256;
  const unsigned short* pkbf = (const unsigned short*)(ws + WS_PKBF);
  const unsigned short* psbf = (const unsigned short*)(ws + WS_PSBF);

  // stage pk tile [64][256] -> [64][264]
  for (int n = 0; n < 4; ++n) {
    int idx = t + 512 * n;                       // 2048 8-elem chunks
    int m = idx >> 5, c8 = idx & 31;
    *(uint4*)&pk_s[m * 264 + c8 * 8] =
      *(const uint4*)&pkbf[(long)(qbase + m) * 256 + c8 * 8];
  }

  const int lane = t & 63, wv = t >> 6;
  const int n16 = lane & 15, quad = lane >> 4;
  const int m0 = (wv >> 2) * 32, s0 = (wv & 3) * 64;
  f32x4 acc[2][4] = {};

  for (int kh = 0; kh < 2; ++kh) {
    __syncthreads();
    for (int n = 0; n < 8; ++n) {
      int idx = t + 512 * n;                     // 4096 8-elem chunks
      int s = idx >> 4, c8 = idx & 15;
      uint4 u = make_uint4(0u, 0u, 0u, 0u);
      if (sbase + s < M_)
        u = *(const uint4*)&psbf[(sbase + s) * 256 + kh * 128 + c8 * 8];
      *(uint4*)&ps_s[s * 136 + c8 * 8] = u;
    }
    __syncthreads();
    const int kb = kh * 128;
    #pragma unroll
    for (int ks = 0; ks < 4; ++ks) {
      bf16x8 a0 = *(const bf16x8*)&pk_s[(m0 + n16) * 264 + kb + ks * 32 + quad * 8];
      bf16x8 a1 = *(const bf16x8*)&pk_s[(m0 + 16 + n16) * 264 + kb + ks * 32 + quad * 8];
      #pragma unroll
      for (int sf = 0; sf < 4; ++sf) {
        bf16x8 b = *(const bf16x8*)&ps_s[(s0 + sf * 16 + n16) * 136 + ks * 32 + quad * 8];
        acc[0][sf] = __builtin_amdgcn_mfma_f32_16x16x32_bf16(a0, b, acc[0][sf], 0, 0, 0);
        acc[1][sf] = __builtin_amdgcn_mfma_f32_16x16x32_bf16(a1, b, acc[1][sf], 0, 0, 0);
      }
    }
  }
  __syncthreads();
  // write sim tile to LDS (C/D layout: col = lane&15, row = quad*4+reg)
  #pragma unroll
  for (int qf = 0; qf < 2; ++qf)
    #pragma unroll
    for (int sf = 0; sf < 4; ++sf)
      #pragma unroll
      for (int r = 0; r < 4; ++r)
        simt[(m0 + qf * 16 + quad * 4 + r) * SIMW + s0 + sf * 16 + n16] = acc[qf][sf][r];
  __syncthreads();
  // per-row top-8 over 256 slots: 2 threads/row scan 128 each, then merge
  if (t < 128) {
    int row = t >> 1, half = t & 1;
    int sv = (int)(M_ - sbase);
    int lo = half * 128;
    int mmax = sv - lo; if (mmax > 128) mmax = 128; if (mmax < 0) mmax = 0;
    float tv[8]; int ti[8];
    #pragma unroll
    for (int q = 0; q < 8; ++q) { tv[q] = -3.0e38f; ti[q] = 0x7FFFFFFF; }
    for (int m = 0; m < mmax; ++m) {
      float v = simt[row * SIMW + lo + m];
      if (v > tv[7]) {
        int s = (int)(sbase + lo + m);
        bool placed = false;
        #pragma unroll
        for (int q = 7; q >= 1; --q) {
          if (!placed) {
            if (v > tv[q - 1]) { tv[q] = tv[q - 1]; ti[q] = ti[q - 1]; }
            else { tv[q] = v; ti[q] = s; placed = true; }
          }
        }
        if (!placed) { tv[0] = v; ti[0] = s; }
      }
    }
    #pragma unroll
    for (int q = 0; q < 8; ++q) { candv[t * 8 + q] = tv[q]; candi[t * 8 + q] = ti[q]; }
  }
  __syncthreads();
  if (t < 64) {
    const float* av = &candv[(2 * t) * 8];
    const float* bv = &candv[(2 * t + 1) * 8];
    const int* ai = &candi[(2 * t) * 8];
    const int* bi = &candi[(2 * t + 1) * 8];
    float* cv = ws + WS_CANDV;
    int* ci = (int*)(ws + WS_CANDI);
    long ob = (long)(qbase + t) * CPR2 + (long)stile * 8;
    int ia = 0, ib = 0;
    #pragma unroll
    for (int q = 0; q < 8; ++q) {
      bool ta;
      if (ia >= 8) ta = false;
      else if (ib >= 8) ta = true;
      else {
        float va = av[ia], vb = bv[ib];
        ta = (va > vb) || (va == vb && ai[ia] <= bi[ib]);
      }
      if (ta) { cv[ob + q] = av[ia]; ci[ob + q] = ai[ia]; ++ia; }
      else    { cv[ob + q] = bv[ib]; ci[ob + q] = bi[ib]; ++ib; }
    }
  }
}

// ---------------- K4: per-row merge -> top16 -> f64 rescore -> top8 ----------------
__global__ void k_topk(const void* key_store, const void* idx_store,
                       float* ws, void* dout) {
  __shared__ unsigned long long keys[256 * 16];
  __shared__ unsigned long long redk[256];
  __shared__ unsigned long long res[16];
  __shared__ int cidx[16];
  __shared__ double rv[16];
  const int isbf = *(const int*)ws;
  const int t = threadIdx.x, b = blockIdx.x;
  unsigned long long* ml = &keys[t * 16];
  #pragma unroll
  for (int q = 0; q < 16; ++q) ml[q] = 0ull;
  const float* cv = ws + WS_CANDV;
  const int* ci = (const int*)(ws + WS_CANDI);
  long base = (long)b * CPR2;
  for (int cc = t; cc < CPR2; cc += 256) {
    float v = cv[base + cc];
    unsigned id = (unsigned)ci[base + cc];
    unsigned bb = __float_as_uint(v);
    unsigned o = (bb & 0x80000000u) ? ~bb : (bb | 0x80000000u);
    unsigned long long key = ((unsigned long long)o << 32) |
                             (unsigned long long)(0xFFFFFFFFu - id);
    if (key > ml[15]) {
      int q = 15;
      while (q > 0 && key > ml[q - 1]) { ml[q] = ml[q - 1]; --q; }
      ml[q] = key;
    }
  }
  __syncthreads();
  int h = 0;
  for (int r = 0; r < 16; ++r) {
    redk[t] = (h < 16) ? ml[h] : 0ull;
    __syncthreads();
    for (int s = 128; s > 0; s >>= 1) {
      if (t < s) { if (redk[t + s] > redk[t]) redk[t] = redk[t + s]; }
      __syncthreads();
    }
    unsigned long long win = redk[0];
    if (h < 16 && ml[h] == win) ++h;
    if (t == 0) res[r] = win;
    __syncthreads();
  }
  if (t < 16) cidx[t] = (int)(0xFFFFFFFFu - (unsigned)(res[t] & 0xFFFFFFFFu));
  __syncthreads();
  // f64 rescore of 16 candidates (16 threads per candidate)
  {
    int cand = t >> 4, p = t & 15;
    long m = (long)cidx[cand];
    double dp = 0.0, nr = 0.0;
    for (int ii = 0; ii < 16; ++ii) {
      int i = p * 16 + ii;
      double s = (double)ws[WS_KPB + i];
      const float* wrow = ws + WS_KPW + (long)i * 256;
      if (isbf) {
        const unsigned short* kr = (const unsigned short*)key_store + m * 256;
        for (int j = 0; j < 256; ++j)
          s += (double)__uint_as_float((unsigned)kr[j] << 16) * (double)wrow[j];
      } else {
        const float* kr = (const float*)key_store + m * 256;
        for (int j = 0; j < 256; ++j)
          s += (double)kr[j] * (double)wrow[j];
      }
      dp += s * (double)ws[WS_PKN + (long)b * 256 + i];
      nr += s * s;
    }
    dp += __shfl_xor(dp, 1); nr += __shfl_xor(nr, 1);
    dp += __shfl_xor(dp, 2); nr += __shfl_xor(nr, 2);
    dp += __shfl_xor(dp, 4); nr += __shfl_xor(nr, 4);
    dp += __shfl_xor(dp, 8); nr += __shfl_xor(nr, 8);
    if (p == 0) rv[cand] = dp / fmax(sqrt(nr), 1e-8);
  }
  __syncthreads();
  if (t == 0) {
    int ordr[16];
    for (int q = 0; q < 16; ++q) ordr[q] = q;
    for (int a = 0; a < 8; ++a) {
      int best = a;
      for (int x = a + 1; x < 16; ++x) {
        int xi = ordr[x], bi = ordr[best];
        if (rv[xi] > rv[bi] || (rv[xi] == rv[bi] && cidx[xi] < cidx[bi])) best = x;
      }
      int tmp = ordr[a]; ordr[a] = ordr[best]; ordr[best] = tmp;
    }
    int* seli = (int*)(ws + WS_SELI);
    for (int r = 0; r < 8; ++r) {
      int m = cidx[ordr[r]];
      stf(dout, OUT_IDX + b * 8 + r, (float)m, isbf);
      stf(dout, OUT_SIMV + b * 8 + r, (float)rv[ordr[r]], isbf);
      stf(dout, OUT_SELIDX + b * 8 + r, ldf(idx_store, m, isbf), isbf);
      seli[b * 8 + r] = m;
    }
  }
}

// ---------------- K5: GAT compose + count-sketch + circular conv ----------------
__global__ void k_compose(const void* value_store, const int* h1, const int* h2,
                          float* ws, void* dout) {
  __shared__ float feats[9][512];
  __shared__ float Wh[9][512];
  __shared__ float g0[9][8];
  __shared__ float sd_[2][9][8];
  __shared__ float psi1[512], psi2[512], pooled[512];
  __shared__ float wk[9];
  __shared__ float redz[40];
  __shared__ int sel[8];
  const int isbf = *(const int*)ws;
  const int t = threadIdx.x, b = blockIdx.x;
  if (t < 8) sel[t] = ((const int*)(ws + WS_SELI))[b * 8 + t];
  feats[0][t]       = ws[WS_OUT + (long)b * 512 + t];
  feats[0][t + 256] = ws[WS_OUT + (long)b * 512 + t + 256];
  __syncthreads();
  for (int n = 0; n < 16; ++n) {
    int e = t + 256 * n;
    int r = e >> 9, d = e & 511;
    feats[1 + r][d] = ldf(value_store, (long)sel[r] * 512 + d, isbf);
  }
  __syncthreads();
  {
    const int he0 = t, he1 = t + 256;
    float a0[9] = {}, a1[9] = {};
    const float* gw = ws + WS_GATW;
    for (int d = 0; d < 512; ++d) {
      float w0 = gw[(long)d * 512 + he0];
      float w1 = gw[(long)d * 512 + he1];
      #pragma unroll
      for (int k = 0; k < 9; ++k) {
        float a = feats[k][d];
        a0[k] += a * w0;
        a1[k] += a * w1;
      }
    }
    #pragma unroll
    for (int k = 0; k < 9; ++k) { Wh[k][he0] = a0[k]; Wh[k][he1] = a1[k]; }
  }
  __syncthreads();
  if (t < 144) {
    int k = t >> 4, rem = t & 15, hh = rem >> 1, sdx = rem & 1;
    const float* av = ws + (sdx ? WS_GAD : WS_GAS) + hh * 64;
    float s = 0.f;
    for (int e = 0; e < 64; ++e) s += Wh[k][hh * 64 + e] * av[e];
    sd_[sdx][k][hh] = s;
  }
  __syncthreads();
  if (t < 8) {
    float L[9], mx = -3e38f;
    for (int j = 0; j < 9; ++j) {
      float x = sd_[0][0][t] + sd_[1][j][t];
      L[j] = x > 0.f ? x : 0.2f * x;
      mx = fmaxf(mx, L[j]);
    }
    float ssum = 0.f;
    for (int j = 0; j < 9; ++j) { L[j] = expf(L[j] - mx); ssum += L[j]; }
    for (int j = 0; j < 9; ++j) g0[j][t] = L[j] / ssum;
  }
  __syncthreads();
  for (int n = 0; n < 3; ++n) {
    int e = t + 256 * n;
    if (e < 648) {
      int i = e / 72, rem = e % 72, j = rem >> 3, hh = rem & 7;
      float v = (i == 0) ? g0[j][hh] : ((i == j) ? 1.0f : 0.0f);
      stf(dout, OUT_GATT + (long)b * 648 + e, v, isbf);
    }
  }
  __syncthreads();
  #pragma unroll
  for (int i = 0; i < 9; ++i) {
    for (int half = 0; half < 2; ++half) {
      int d = t + half * 256;
      float x;
      if (i == 0) {
        int hh = d >> 6;
        x = 0.f;
        #pragma unroll
        for (int j = 0; j < 9; ++j) x += g0[j][hh] * Wh[j][d];
      } else x = Wh[i][d];
      feats[i][d] = x > 0.f ? x : expm1f(x);
    }
  }
  __syncthreads();
  {
    float part[9];
    const float* aw = ws + WS_GAW;
    #pragma unroll
    for (int k = 0; k < 9; ++k)
      part[k] = feats[k][t] * aw[t] + feats[k][t + 256] * aw[t + 256];
    #pragma unroll
    for (int k = 0; k < 9; ++k) {
      float s = part[k];
      s += __shfl_xor(s, 1);  s += __shfl_xor(s, 2);  s += __shfl_xor(s, 4);
      s += __shfl_xor(s, 8);  s += __shfl_xor(s, 16); s += __shfl_xor(s, 32);
      if ((t & 63) == 0) redz[(t >> 6) * 9 + k] = s;
    }
  }
  __syncthreads();
  if (t == 0) {
    float l[9], mx = -3e38f;
    for (int k = 0; k < 9; ++k) {
      l[k] = redz[k] + redz[9 + k] + redz[18 + k] + redz[27 + k] + ws[WS_GAB];
      mx = fmaxf(mx, l[k]);
    }
    float ssum = 0.f;
    for (int k = 0; k < 9; ++k) { l[k] = expf(l[k] - mx); ssum += l[k]; }
    for (int k = 0; k < 9; ++k) wk[k] = l[k] / ssum;
  }
  __syncthreads();
  for (int half = 0; half < 2; ++half) {
    int d = t + half * 256;
    float s = 0.f;
    #pragma unroll
    for (int k = 0; k < 9; ++k) s += wk[k] * feats[k][d];
    pooled[d] = s;
    psi1[d] = 0.f; psi2[d] = 0.f;
  }
  __syncthreads();
  for (int half = 0; half < 2; ++half) {
    int j = t + half * 256;
    atomicAdd(&psi1[h1[j]], ws[WS_OUT + (long)b * 512 + j] * ws[WS_S1 + j]);
    atomicAdd(&psi2[h2[j]], pooled[j] * ws[WS_S2 + j]);
  }
  __syncthreads();
  for (int half = 0; half < 2; ++half) {
    int tt = t + half * 256;
    float s = 0.f;
    for (int j = 0; j < 512; ++j) s += psi1[j] * psi2[(tt - j) & 511];
    stf(dout, OUT_COMPOSED + (long)b * 1024 + tt, s, isbf);
    stf(dout, OUT_COMPOSED + (long)b * 1024 + 512 + tt,
        ws[WS_OUT + (long)b * 512 + tt], isbf);
  }
}

// ---------------- launch ----------------
extern "C" void kernel_launch(void* const* d_in, const int* in_sizes, int n_in,
                              void* d_out, int out_size, void* d_ws, size_t ws_size,
                              hipStream_t stream) {
  float* ws = (float*)d_ws;
  k_detect<<<1, 64, 0, stream>>>((const unsigned*)d_in[15], (int*)d_ws);
  k_prep<<<512, 256, 0, stream>>>(d_in[1], d_in[6], d_in[7], d_in[0], d_in[8],
                                  d_in[9], d_in[10], d_in[11], d_in[12],
                                  d_in[15], d_in[16], ws);
  k_pk<<<64, 256, 0, stream>>>(ws);
  k_ps<<<NPS, 256, 0, stream>>>(d_in[3], ws);
  size_t smem = 103424;                         // pk 33792 + ps 69632 bytes
  hipFuncSetAttribute((const void*)k_sim,
                      hipFuncAttributeMaxDynamicSharedMemorySize, (int)smem);
  k_sim<<<NST * 8, 512, smem, stream>>>(ws);
  k_topk<<<512, 256, 0, stream>>>(d_in[3], d_in[5], ws, d_out);
  k_compose<<<512, 256, 0, stream>>>(d_in[4], (const int*)d_in[13],
                                     (const int*)d_in[14], ws, d_out);
}